// Round 13
// baseline (395.059 us; speedup 1.0000x reference)
//
#include <hip/hip_runtime.h>
#include <hip/hip_fp16.h>
#include <math.h>

#define N_CONT 99996
#define NN     100000
#define NE     1600000
#define BB     4096
#define CC     10

typedef unsigned int  uint;
typedef unsigned short ushort;
typedef unsigned long long ull;

// f32 -> bf16 bits, round-to-nearest-even
__device__ __forceinline__ uint f2bf(float f) {
    uint u = __float_as_uint(f);
    return (u + 0x7FFFu + ((u >> 16) & 1u)) >> 16;
}
__device__ __forceinline__ float bflo(uint u) { return __uint_as_float(u << 16); }
__device__ __forceinline__ float bfhi(uint u) { return __uint_as_float(u & 0xFFFF0000u); }

// ---------------- init: dc=0 (packed deg|cnt), pooled=0, offs[NN]=NE ----------
__global__ void k_init(ull* __restrict__ dc, float* __restrict__ pooled,
                       int* __restrict__ offs) {
    int i = blockIdx.x * 256 + threadIdx.x;
    if (i < NN) dc[i] = 0ull;
    if (i < 128) pooled[i] = 0.0f;
    if (i == 0)  offs[NN] = NE;        // total edge count is fixed
}

// ---------------- deg+cnt fused: dc[col] += (1<<40) | fx24(ew); rank out ------
__global__ void k_degcnt(const int* __restrict__ coli, const float* __restrict__ ew,
                         ull* __restrict__ dc, int* __restrict__ rank) {
    int e = blockIdx.x * 256 + threadIdx.x;
    if (e < NE) {
        int c = coli[e];
        ull v = (1ull << 40) | (ull)(ew[e] * 16777216.0f + 0.5f);
        ull old = atomicAdd(&dc[c], v);
        rank[e] = (int)(old >> 40);
    }
}

// ---------------- unpack: cnt = dc>>40; dis = rsqrt(1 + fx24) -----------------
__global__ void k_dis(const ull* __restrict__ dc, float* __restrict__ dis,
                      int* __restrict__ cnt) {
    int i = blockIdx.x * 256 + threadIdx.x;
    if (i < NN) {
        ull v = dc[i];
        cnt[i] = (int)(v >> 40);
        float deg = 1.0f + (float)(v & 0xFFFFFFFFFFull) * 5.9604644775390625e-8f;
        dis[i] = rsqrtf(deg);
    }
}

// ---------------- scan pass 1: per-block sums of cnt --------------------------
__global__ void k_scan1(const int* __restrict__ cnt, int* __restrict__ bsum) {
    __shared__ int red[256];
    int t = threadIdx.x;
    int i = blockIdx.x * 256 + t;
    red[t] = (i < NN) ? cnt[i] : 0;
    __syncthreads();
    for (int off = 128; off; off >>= 1) {
        if (t < off) red[t] += red[t + off];
        __syncthreads();
    }
    if (t == 0) bsum[blockIdx.x] = red[0];
}

// ---------------- scan pass 2: exclusive scan of 391 block sums ---------------
__global__ __launch_bounds__(512) void k_scan2(const int* __restrict__ bsum,
                                               int* __restrict__ boff) {
    __shared__ int s[512];
    int t = threadIdx.x;
    int v = (t < 391) ? bsum[t] : 0;
    s[t] = v;
    __syncthreads();
    for (int off = 1; off < 512; off <<= 1) {
        int u = (t >= off) ? s[t - off] : 0;
        __syncthreads();
        s[t] += u;
        __syncthreads();
    }
    if (t < 391) boff[t] = s[t] - v;   // exclusive
}

// ---------------- scan pass 3: block-local exclusive scan + block offset ------
__global__ void k_scan3(const int* __restrict__ cnt, const int* __restrict__ boff,
                        int* __restrict__ offs) {
    __shared__ int s[256];
    int t = threadIdx.x;
    int i = blockIdx.x * 256 + t;
    int v = (i < NN) ? cnt[i] : 0;
    s[t] = v;
    __syncthreads();
    for (int off = 1; off < 256; off <<= 1) {
        int u = (t >= off) ? s[t - off] : 0;
        __syncthreads();
        s[t] += u;
        __syncthreads();
    }
    int ex = s[t] - v + boff[blockIdx.x];
    if (i < NN) offs[i] = ex;
}

// ---------------- cat embed: catf[k][d] = sum_c cat_x[k][d][c]*emb_w[k][c] ----
__global__ void k_cat(const float* __restrict__ cat_x, const float* __restrict__ emb_w,
                      float* __restrict__ catf) {
    int i = blockIdx.x * 256 + threadIdx.x;
    if (i < 512) {
        int kf = i >> 7, d = i & 127;
        const float* cx = cat_x + (size_t)(kf * 128 + d) * 10;
        const float* em = emb_w + kf * 10;
        float s = 0.f;
        #pragma unroll
        for (int c = 0; c < 10; ++c) s += cx[c] * em[c];
        catf[i] = s;
    }
}

// ---------------- GEMM: xw = bf16(x @ W) --------------------------------------
// 128x128 block tile, 8x8 per-thread micro-tile, K chunked at 32.
__global__ __launch_bounds__(256, 3) void k_gemm(
        const float* __restrict__ num_x, const float* __restrict__ catf,
        const float* __restrict__ W, uint* __restrict__ xwb) {
    __shared__ float sW[32 * 128];     // 16 KB
    __shared__ float sX[128 * 36];     // 18 KB
    const int tid = threadIdx.x;
    const int cgi = tid & 15;
    const int rgi = tid >> 4;
    const int cg  = cgi * 8;
    const int rg  = rgi * 8;
    const int rb  = blockIdx.x * 128;

    float4 acc[8][2];
    #pragma unroll
    for (int j = 0; j < 8; ++j) {
        acc[j][0] = make_float4(0.f, 0.f, 0.f, 0.f);
        acc[j][1] = make_float4(0.f, 0.f, 0.f, 0.f);
    }

    for (int kb = 0; kb < 128; kb += 32) {
        for (int m = tid; m < 1024; m += 256) {
            int k = m >> 5, f = (m & 31) * 4;
            *(float4*)&sW[k * 128 + f] = *(const float4*)&W[(size_t)(kb + k) * 128 + f];
        }
        for (int m = tid; m < 1024; m += 256) {
            int r = m >> 3, kq = (m & 7) * 4;
            int gr = rb + r;
            float4 v = make_float4(0.f, 0.f, 0.f, 0.f);
            if (gr < N_CONT)      v = *(const float4*)&num_x[(size_t)gr * 128 + kb + kq];
            else if (gr < NN)     v = *(const float4*)&catf[(size_t)(gr - N_CONT) * 128 + kb + kq];
            *(float4*)&sX[r * 36 + kq] = v;
        }
        __syncthreads();

        for (int k4 = 0; k4 < 32; k4 += 4) {
            float4 xv[8];
            #pragma unroll
            for (int j = 0; j < 8; ++j) xv[j] = *(const float4*)&sX[(rg + j) * 36 + k4];
            #pragma unroll
            for (int t = 0; t < 4; ++t) {
                const float4 wa = *(const float4*)&sW[(k4 + t) * 128 + cg];
                const float4 wb = *(const float4*)&sW[(k4 + t) * 128 + cg + 4];
                #pragma unroll
                for (int j = 0; j < 8; ++j) {
                    const float xk = (t == 0) ? xv[j].x : (t == 1) ? xv[j].y
                                   : (t == 2) ? xv[j].z : xv[j].w;
                    acc[j][0].x += xk * wa.x;  acc[j][0].y += xk * wa.y;
                    acc[j][0].z += xk * wa.z;  acc[j][0].w += xk * wa.w;
                    acc[j][1].x += xk * wb.x;  acc[j][1].y += xk * wb.y;
                    acc[j][1].z += xk * wb.z;  acc[j][1].w += xk * wb.w;
                }
            }
        }
        __syncthreads();
    }

    #pragma unroll
    for (int j = 0; j < 8; ++j) {
        int gr = rb + rg + j;
        if (gr < NN) {
            uint4 p;
            p.x = f2bf(acc[j][0].x) | (f2bf(acc[j][0].y) << 16);
            p.y = f2bf(acc[j][0].z) | (f2bf(acc[j][0].w) << 16);
            p.z = f2bf(acc[j][1].x) | (f2bf(acc[j][1].y) << 16);
            p.w = f2bf(acc[j][1].z) | (f2bf(acc[j][1].w) << 16);
            *(uint4*)&xwb[(size_t)gr * 64 + cgi * 4] = p;
        }
    }
}

// ---------------- CSR fill: sorted[offs[col]+rank[e]] = row<<15|f16(dis*ew) ---
__global__ void k_fill(const int* __restrict__ rowi, const int* __restrict__ coli,
                       const float* __restrict__ ew, const float* __restrict__ dis,
                       const int* __restrict__ offs, const int* __restrict__ rank,
                       uint* __restrict__ sorted) {
    int e = blockIdx.x * 256 + threadIdx.x;
    if (e < NE) {
        int r = rowi[e], c = coli[e];
        float nr = dis[r] * ew[e];                    // in [0,1]
        ushort hb = __half_as_ushort(__float2half_rn(nr));  // sign bit always 0
        sorted[offs[c] + rank[e]] = ((uint)r << 15) | (uint)hb;
    }
}

// ---------------- gather: h[c] = xw[c]/deg + dis[c]*sum_e f16nrm*xw[row] ------
// Wave per node; 4 edge-slots x 16 dim-lanes (uint4 = 8 dims, 16 B/lane).
// Manual 2-wide software pipeline per slot: both sorted entries issued
// together, then both row loads together -> 2 independent row reads in
// flight per slot (8 per wave), no compiler-unroll dependence.
__global__ __launch_bounds__(256) void k_gather(
        const uint4* __restrict__ xwb4, const float* __restrict__ dis,
        const uint* __restrict__ sorted, const int* __restrict__ offs,
        float* __restrict__ pooled) {
    __shared__ float red[4][128];
    const int lane = threadIdx.x & 63;
    const int wib  = threadIdx.x >> 6;                     // wave in block 0..3
    const int slot = lane >> 4;                            // edge slot 0..3
    const int dg   = lane & 15;                            // dim group: 8 dims
    const int wid  = (blockIdx.x * 256 + threadIdx.x) >> 6;
    const int nw   = (gridDim.x * 256) >> 6;

    float pacc[8] = {0.f, 0.f, 0.f, 0.f, 0.f, 0.f, 0.f, 0.f};
    for (int i = wid; i < NN; i += nw) {
        float di = dis[i];
        float s  = di * di;                                // self-loop 1/deg
        uint4 sv = xwb4[(size_t)i * 16 + dg];
        float ea[8] = {0.f, 0.f, 0.f, 0.f, 0.f, 0.f, 0.f, 0.f};
        const int e0 = offs[i + 1];
        int k = offs[i] + slot;
        // 2-wide: k and k+4 both valid while k+4 < e0
        for (; k + 4 < e0; k += 8) {
            uint pv0 = sorted[k];
            uint pv1 = sorted[k + 4];
            int  r0  = (int)(pv0 >> 15);
            int  r1  = (int)(pv1 >> 15);
            float n0 = __half2float(__ushort_as_half((ushort)(pv0 & 0x7FFFu)));
            float n1 = __half2float(__ushort_as_half((ushort)(pv1 & 0x7FFFu)));
            uint4 v0 = xwb4[(size_t)r0 * 16 + dg];
            uint4 v1 = xwb4[(size_t)r1 * 16 + dg];
            ea[0] += bflo(v0.x) * n0;  ea[1] += bfhi(v0.x) * n0;
            ea[2] += bflo(v0.y) * n0;  ea[3] += bfhi(v0.y) * n0;
            ea[4] += bflo(v0.z) * n0;  ea[5] += bfhi(v0.z) * n0;
            ea[6] += bflo(v0.w) * n0;  ea[7] += bfhi(v0.w) * n0;
            ea[0] += bflo(v1.x) * n1;  ea[1] += bfhi(v1.x) * n1;
            ea[2] += bflo(v1.y) * n1;  ea[3] += bfhi(v1.y) * n1;
            ea[4] += bflo(v1.z) * n1;  ea[5] += bfhi(v1.z) * n1;
            ea[6] += bflo(v1.w) * n1;  ea[7] += bfhi(v1.w) * n1;
        }
        if (k < e0) {                                      // slot tail (0 or 1)
            uint pv   = sorted[k];
            int  row  = (int)(pv >> 15);
            float nrm = __half2float(__ushort_as_half((ushort)(pv & 0x7FFFu)));
            uint4 v = xwb4[(size_t)row * 16 + dg];
            ea[0] += bflo(v.x) * nrm;  ea[1] += bfhi(v.x) * nrm;
            ea[2] += bflo(v.y) * nrm;  ea[3] += bfhi(v.y) * nrm;
            ea[4] += bflo(v.z) * nrm;  ea[5] += bfhi(v.z) * nrm;
            ea[6] += bflo(v.w) * nrm;  ea[7] += bfhi(v.w) * nrm;
        }
        #pragma unroll
        for (int j = 0; j < 8; ++j) {
            ea[j] += __shfl_xor(ea[j], 16);
            ea[j] += __shfl_xor(ea[j], 32);
        }
        uint sx[4] = {sv.x, sv.y, sv.z, sv.w};
        #pragma unroll
        for (int q = 0; q < 4; ++q) {
            float a0 = bflo(sx[q]) * s + di * ea[2 * q];
            float a1 = bfhi(sx[q]) * s + di * ea[2 * q + 1];
            pacc[2 * q]     += fmaxf(a0, 0.f);
            pacc[2 * q + 1] += fmaxf(a1, 0.f);
        }
    }
    if (lane < 16) {
        #pragma unroll
        for (int j = 0; j < 8; ++j) red[wib][dg * 8 + j] = pacc[j];
    }
    __syncthreads();
    if (threadIdx.x < 128) {
        float v = red[0][threadIdx.x] + red[1][threadIdx.x]
                + red[2][threadIdx.x] + red[3][threadIdx.x];
        atomicAdd(&pooled[threadIdx.x], v);
    }
}

// ---------------- scalar: sbase = dot(pooled/N, fc_w[10:138]) + fc_b ----------
__global__ void k_scal(const float* __restrict__ pooled, const float* __restrict__ fcw,
                       const float* __restrict__ fcb, float* __restrict__ sbase) {
    int lane = threadIdx.x;   // 64
    float v = pooled[lane]      * (1.0f / NN) * fcw[10 + lane]
            + pooled[lane + 64] * (1.0f / NN) * fcw[10 + 64 + lane];
    #pragma unroll
    for (int o = 32; o; o >>= 1) v += __shfl_down(v, o);
    if (lane == 0) sbase[0] = v + fcb[0];
}

// ---------------- out: out[b,:] = vanilla[b,:] / softplus_gate(b) -------------
__global__ void k_out(const float* __restrict__ vanilla, const float* __restrict__ fcw,
                      const float* __restrict__ sbase, float* __restrict__ out) {
    int b = blockIdx.x * 256 + threadIdx.x;
    if (b < BB) {
        float logit = sbase[0];
        const float* vr = vanilla + (size_t)b * 10;
        #pragma unroll
        for (int c = 0; c < 10; ++c) logit += vr[c] * fcw[c];
        float x = 1.1f * logit;
        float sp = fmaxf(x, 0.f) + log1pf(expf(-fabsf(x)));   // stable softplus
        float t  = sp / 1.1f;
        float inv = 1.0f / t;
        #pragma unroll
        for (int c = 0; c < 10; ++c) out[(size_t)b * 10 + c] = vr[c] * inv;
    }
}

extern "C" void kernel_launch(void* const* d_in, const int* in_sizes, int n_in,
                              void* d_out, int out_size, void* d_ws, size_t ws_size,
                              hipStream_t stream) {
    const float* num_x   = (const float*)d_in[0];
    const float* cat_x   = (const float*)d_in[1];
    const float* ew      = (const float*)d_in[2];
    const float* vanilla = (const float*)d_in[3];
    const float* conv_w  = (const float*)d_in[4];
    const float* emb_w   = (const float*)d_in[5];
    const float* fc_w    = (const float*)d_in[6];
    const float* fc_b    = (const float*)d_in[7];
    const int*   ei      = (const int*)d_in[8];
    const int*   rowi    = ei;        // edge_index[0]
    const int*   coli    = ei + NE;   // edge_index[1]

    float* ws     = (float*)d_ws;
    ull*   dc     = (ull*)ws;                 // 100000 x 8B — dead after k_dis
    float* dis    = ws + 200000;              // 100000
    float* catf   = ws + 300000;              // 512
    float* pooled = ws + 300512;              // 128
    float* sbase  = ws + 300640;              // 64 (pad)
    int*   cnt    = (int*)(ws + 300704);      // 100000
    int*   offs   = (int*)(ws + 400704);      // 100001 (pad to 100064)
    int*   rank   = (int*)(ws + 500768);      // 1600000 ints (6.4 MB)
    uint*  sorted = (uint*)(ws + 2100768);    // 1600000 uints (6.4 MB)
    uint*  xwb    = (uint*)(ws + 3700768);    // 6400000 uints (25.6 MB, 16B-aligned)
    // scan scratch overlaps dead dc region (dc unused after k_dis):
    int*   bsum   = (int*)ws;                 // 391 ints
    int*   boff   = (int*)(ws + 512);         // 391 ints
    float* out    = (float*)d_out;

    k_init  <<<391,  256, 0, stream>>>(dc, pooled, offs);
    k_degcnt<<<6250, 256, 0, stream>>>(coli, ew, dc, rank);
    k_dis   <<<391,  256, 0, stream>>>(dc, dis, cnt);
    k_scan1 <<<391,  256, 0, stream>>>(cnt, bsum);
    k_scan2 <<<1,    512, 0, stream>>>(bsum, boff);
    k_scan3 <<<391,  256, 0, stream>>>(cnt, boff, offs);
    k_cat   <<<2,    256, 0, stream>>>(cat_x, emb_w, catf);
    k_gemm  <<<782,  256, 0, stream>>>(num_x, catf, conv_w, xwb);
    k_fill  <<<6250, 256, 0, stream>>>(rowi, coli, ew, dis, offs, rank, sorted);
    k_gather<<<2048, 256, 0, stream>>>((const uint4*)xwb, dis, sorted, offs, pooled);
    k_scal  <<<1,    64,  0, stream>>>(pooled, fc_w, fc_b, sbase);
    k_out   <<<16,   256, 0, stream>>>(vanilla, fc_w, sbase, out);
}

// Round 14
// 371.060 us; speedup vs baseline: 1.0647x; 1.0647x over previous
//
#include <hip/hip_runtime.h>
#include <hip/hip_fp16.h>
#include <math.h>

#define N_CONT 99996
#define NN     100000
#define NE     1600000
#define BB     4096
#define CC     10

typedef unsigned int  uint;
typedef unsigned short ushort;
typedef unsigned long long ull;

// f32 -> bf16 bits, round-to-nearest-even
__device__ __forceinline__ uint f2bf(float f) {
    uint u = __float_as_uint(f);
    return (u + 0x7FFFu + ((u >> 16) & 1u)) >> 16;
}
__device__ __forceinline__ float bflo(uint u) { return __uint_as_float(u << 16); }
__device__ __forceinline__ float bfhi(uint u) { return __uint_as_float(u & 0xFFFF0000u); }

// ---------------- init: dc=0, pooled=0, offs[NN]=NE, + cat embed fused --------
// cat: catf[k][d] = sum_c cat_x[k][d][c]*emb_w[k][c]  (512 outputs, mapped to
// global thread ids [99584,100096) which the 391-block grid covers)
__global__ void k_init(ull* __restrict__ dc, float* __restrict__ pooled,
                       int* __restrict__ offs, const float* __restrict__ cat_x,
                       const float* __restrict__ emb_w, float* __restrict__ catf) {
    int i = blockIdx.x * 256 + threadIdx.x;
    if (i < NN) dc[i] = 0ull;
    if (i < 128) pooled[i] = 0.0f;
    if (i == 0)  offs[NN] = NE;        // total edge count is fixed
    int j = i - 99584;
    if (j >= 0 && j < 512) {
        int kf = j >> 7, d = j & 127;
        const float* cx = cat_x + (size_t)(kf * 128 + d) * 10;
        const float* em = emb_w + kf * 10;
        float s = 0.f;
        #pragma unroll
        for (int c = 0; c < 10; ++c) s += cx[c] * em[c];
        catf[j] = s;
    }
}

// ---------------- deg+cnt fused: dc[col] += (1<<40) | fx24(ew); rank out ------
__global__ void k_degcnt(const int* __restrict__ coli, const float* __restrict__ ew,
                         ull* __restrict__ dc, int* __restrict__ rank) {
    int e = blockIdx.x * 256 + threadIdx.x;
    if (e < NE) {
        int c = coli[e];
        ull v = (1ull << 40) | (ull)(ew[e] * 16777216.0f + 0.5f);
        ull old = atomicAdd(&dc[c], v);
        rank[e] = (int)(old >> 40);
    }
}

// ---------------- unpack + scan pass 1 fused: cnt, dis, per-block sums --------
__global__ void k_dis(const ull* __restrict__ dc, float* __restrict__ dis,
                      int* __restrict__ cnt, int* __restrict__ bsum) {
    __shared__ int red[256];
    int t = threadIdx.x;
    int i = blockIdx.x * 256 + t;
    int c = 0;
    if (i < NN) {
        ull v = dc[i];
        c = (int)(v >> 40);
        cnt[i] = c;
        float deg = 1.0f + (float)(v & 0xFFFFFFFFFFull) * 5.9604644775390625e-8f;
        dis[i] = rsqrtf(deg);
    }
    red[t] = c;
    __syncthreads();
    for (int off = 128; off; off >>= 1) {
        if (t < off) red[t] += red[t + off];
        __syncthreads();
    }
    if (t == 0) bsum[blockIdx.x] = red[0];
}

// ---------------- scan pass 2: exclusive scan of 391 block sums ---------------
__global__ __launch_bounds__(512) void k_scan2(const int* __restrict__ bsum,
                                               int* __restrict__ boff) {
    __shared__ int s[512];
    int t = threadIdx.x;
    int v = (t < 391) ? bsum[t] : 0;
    s[t] = v;
    __syncthreads();
    for (int off = 1; off < 512; off <<= 1) {
        int u = (t >= off) ? s[t - off] : 0;
        __syncthreads();
        s[t] += u;
        __syncthreads();
    }
    if (t < 391) boff[t] = s[t] - v;   // exclusive
}

// ---------------- scan pass 3: block-local exclusive scan + block offset ------
__global__ void k_scan3(const int* __restrict__ cnt, const int* __restrict__ boff,
                        int* __restrict__ offs) {
    __shared__ int s[256];
    int t = threadIdx.x;
    int i = blockIdx.x * 256 + t;
    int v = (i < NN) ? cnt[i] : 0;
    s[t] = v;
    __syncthreads();
    for (int off = 1; off < 256; off <<= 1) {
        int u = (t >= off) ? s[t - off] : 0;
        __syncthreads();
        s[t] += u;
        __syncthreads();
    }
    int ex = s[t] - v + boff[blockIdx.x];
    if (i < NN) offs[i] = ex;
}

// ---------------- GEMM: xw = bf16(x @ W) --------------------------------------
// 128x128 block tile, 8x8 per-thread micro-tile, K chunked at 32.
__global__ __launch_bounds__(256, 3) void k_gemm(
        const float* __restrict__ num_x, const float* __restrict__ catf,
        const float* __restrict__ W, uint* __restrict__ xwb) {
    __shared__ float sW[32 * 128];     // 16 KB
    __shared__ float sX[128 * 36];     // 18 KB
    const int tid = threadIdx.x;
    const int cgi = tid & 15;
    const int rgi = tid >> 4;
    const int cg  = cgi * 8;
    const int rg  = rgi * 8;
    const int rb  = blockIdx.x * 128;

    float4 acc[8][2];
    #pragma unroll
    for (int j = 0; j < 8; ++j) {
        acc[j][0] = make_float4(0.f, 0.f, 0.f, 0.f);
        acc[j][1] = make_float4(0.f, 0.f, 0.f, 0.f);
    }

    for (int kb = 0; kb < 128; kb += 32) {
        for (int m = tid; m < 1024; m += 256) {
            int k = m >> 5, f = (m & 31) * 4;
            *(float4*)&sW[k * 128 + f] = *(const float4*)&W[(size_t)(kb + k) * 128 + f];
        }
        for (int m = tid; m < 1024; m += 256) {
            int r = m >> 3, kq = (m & 7) * 4;
            int gr = rb + r;
            float4 v = make_float4(0.f, 0.f, 0.f, 0.f);
            if (gr < N_CONT)      v = *(const float4*)&num_x[(size_t)gr * 128 + kb + kq];
            else if (gr < NN)     v = *(const float4*)&catf[(size_t)(gr - N_CONT) * 128 + kb + kq];
            *(float4*)&sX[r * 36 + kq] = v;
        }
        __syncthreads();

        for (int k4 = 0; k4 < 32; k4 += 4) {
            float4 xv[8];
            #pragma unroll
            for (int j = 0; j < 8; ++j) xv[j] = *(const float4*)&sX[(rg + j) * 36 + k4];
            #pragma unroll
            for (int t = 0; t < 4; ++t) {
                const float4 wa = *(const float4*)&sW[(k4 + t) * 128 + cg];
                const float4 wb = *(const float4*)&sW[(k4 + t) * 128 + cg + 4];
                #pragma unroll
                for (int j = 0; j < 8; ++j) {
                    const float xk = (t == 0) ? xv[j].x : (t == 1) ? xv[j].y
                                   : (t == 2) ? xv[j].z : xv[j].w;
                    acc[j][0].x += xk * wa.x;  acc[j][0].y += xk * wa.y;
                    acc[j][0].z += xk * wa.z;  acc[j][0].w += xk * wa.w;
                    acc[j][1].x += xk * wb.x;  acc[j][1].y += xk * wb.y;
                    acc[j][1].z += xk * wb.z;  acc[j][1].w += xk * wb.w;
                }
            }
        }
        __syncthreads();
    }

    #pragma unroll
    for (int j = 0; j < 8; ++j) {
        int gr = rb + rg + j;
        if (gr < NN) {
            uint4 p;
            p.x = f2bf(acc[j][0].x) | (f2bf(acc[j][0].y) << 16);
            p.y = f2bf(acc[j][0].z) | (f2bf(acc[j][0].w) << 16);
            p.z = f2bf(acc[j][1].x) | (f2bf(acc[j][1].y) << 16);
            p.w = f2bf(acc[j][1].z) | (f2bf(acc[j][1].w) << 16);
            *(uint4*)&xwb[(size_t)gr * 64 + cgi * 4] = p;
        }
    }
}

// ---------------- CSR fill: sorted[offs[col]+rank[e]] = row<<15|f16(dis*ew) ---
__global__ void k_fill(const int* __restrict__ rowi, const int* __restrict__ coli,
                       const float* __restrict__ ew, const float* __restrict__ dis,
                       const int* __restrict__ offs, const int* __restrict__ rank,
                       uint* __restrict__ sorted) {
    int e = blockIdx.x * 256 + threadIdx.x;
    if (e < NE) {
        int r = rowi[e], c = coli[e];
        float nr = dis[r] * ew[e];                    // in [0,1]
        ushort hb = __half_as_ushort(__float2half_rn(nr));  // sign bit always 0
        sorted[offs[c] + rank[e]] = ((uint)r << 15) | (uint)hb;
    }
}

// ---------------- gather: h[c] = xw[c]/deg + dis[c]*sum_e f16nrm*xw[row] ------
// Wave per node; 4 edge-slots x 16 dim-lanes (uint4 = 8 dims, 16 B/lane).
// Key schedule: the NEXT pair's sorted[] entries are issued BEFORE the
// current pair's row loads are consumed -> the sorted->row dependent chain
// is decoupled; exposed latency per iteration = row loads only.
__global__ __launch_bounds__(256) void k_gather(
        const uint4* __restrict__ xwb4, const float* __restrict__ dis,
        const uint* __restrict__ sorted, const int* __restrict__ offs,
        float* __restrict__ pooled) {
    __shared__ float red[4][128];
    const int lane = threadIdx.x & 63;
    const int wib  = threadIdx.x >> 6;                     // wave in block 0..3
    const int slot = lane >> 4;                            // edge slot 0..3
    const int dg   = lane & 15;                            // dim group: 8 dims
    const int wid  = (blockIdx.x * 256 + threadIdx.x) >> 6;
    const int nw   = (gridDim.x * 256) >> 6;

    float pacc[8] = {0.f, 0.f, 0.f, 0.f, 0.f, 0.f, 0.f, 0.f};
    for (int i = wid; i < NN; i += nw) {
        float di = dis[i];
        float s  = di * di;                                // self-loop 1/deg
        uint4 sv = xwb4[(size_t)i * 16 + dg];
        float ea[8] = {0.f, 0.f, 0.f, 0.f, 0.f, 0.f, 0.f, 0.f};
        const int e0 = offs[i + 1];
        int k = offs[i] + slot;
        uint pv0 = (k     < e0) ? sorted[k]     : 0u;
        uint pv1 = (k + 4 < e0) ? sorted[k + 4] : 0u;
        while (k + 4 < e0) {
            const int kn = k + 8;
            uint q0 = (kn     < e0) ? sorted[kn]     : 0u;  // prefetch next pair
            uint q1 = (kn + 4 < e0) ? sorted[kn + 4] : 0u;
            float n0 = __half2float(__ushort_as_half((ushort)(pv0 & 0x7FFFu)));
            float n1 = __half2float(__ushort_as_half((ushort)(pv1 & 0x7FFFu)));
            uint4 v0 = xwb4[(size_t)(pv0 >> 15) * 16 + dg];
            uint4 v1 = xwb4[(size_t)(pv1 >> 15) * 16 + dg];
            ea[0] += bflo(v0.x) * n0;  ea[1] += bfhi(v0.x) * n0;
            ea[2] += bflo(v0.y) * n0;  ea[3] += bfhi(v0.y) * n0;
            ea[4] += bflo(v0.z) * n0;  ea[5] += bfhi(v0.z) * n0;
            ea[6] += bflo(v0.w) * n0;  ea[7] += bfhi(v0.w) * n0;
            ea[0] += bflo(v1.x) * n1;  ea[1] += bfhi(v1.x) * n1;
            ea[2] += bflo(v1.y) * n1;  ea[3] += bfhi(v1.y) * n1;
            ea[4] += bflo(v1.z) * n1;  ea[5] += bfhi(v1.z) * n1;
            ea[6] += bflo(v1.w) * n1;  ea[7] += bfhi(v1.w) * n1;
            pv0 = q0; pv1 = q1; k = kn;
        }
        if (k < e0) {                                      // slot tail (<=1)
            float nrm = __half2float(__ushort_as_half((ushort)(pv0 & 0x7FFFu)));
            uint4 v = xwb4[(size_t)(pv0 >> 15) * 16 + dg];
            ea[0] += bflo(v.x) * nrm;  ea[1] += bfhi(v.x) * nrm;
            ea[2] += bflo(v.y) * nrm;  ea[3] += bfhi(v.y) * nrm;
            ea[4] += bflo(v.z) * nrm;  ea[5] += bfhi(v.z) * nrm;
            ea[6] += bflo(v.w) * nrm;  ea[7] += bfhi(v.w) * nrm;
        }
        #pragma unroll
        for (int j = 0; j < 8; ++j) {
            ea[j] += __shfl_xor(ea[j], 16);
            ea[j] += __shfl_xor(ea[j], 32);
        }
        uint sx[4] = {sv.x, sv.y, sv.z, sv.w};
        #pragma unroll
        for (int q = 0; q < 4; ++q) {
            float a0 = bflo(sx[q]) * s + di * ea[2 * q];
            float a1 = bfhi(sx[q]) * s + di * ea[2 * q + 1];
            pacc[2 * q]     += fmaxf(a0, 0.f);
            pacc[2 * q + 1] += fmaxf(a1, 0.f);
        }
    }
    if (lane < 16) {
        #pragma unroll
        for (int j = 0; j < 8; ++j) red[wib][dg * 8 + j] = pacc[j];
    }
    __syncthreads();
    if (threadIdx.x < 128) {
        float v = red[0][threadIdx.x] + red[1][threadIdx.x]
                + red[2][threadIdx.x] + red[3][threadIdx.x];
        atomicAdd(&pooled[threadIdx.x], v);
    }
}

// ---------------- scalar: sbase = dot(pooled/N, fc_w[10:138]) + fc_b ----------
__global__ void k_scal(const float* __restrict__ pooled, const float* __restrict__ fcw,
                       const float* __restrict__ fcb, float* __restrict__ sbase) {
    int lane = threadIdx.x;   // 64
    float v = pooled[lane]      * (1.0f / NN) * fcw[10 + lane]
            + pooled[lane + 64] * (1.0f / NN) * fcw[10 + 64 + lane];
    #pragma unroll
    for (int o = 32; o; o >>= 1) v += __shfl_down(v, o);
    if (lane == 0) sbase[0] = v + fcb[0];
}

// ---------------- out: out[b,:] = vanilla[b,:] / softplus_gate(b) -------------
__global__ void k_out(const float* __restrict__ vanilla, const float* __restrict__ fcw,
                      const float* __restrict__ sbase, float* __restrict__ out) {
    int b = blockIdx.x * 256 + threadIdx.x;
    if (b < BB) {
        float logit = sbase[0];
        const float* vr = vanilla + (size_t)b * 10;
        #pragma unroll
        for (int c = 0; c < 10; ++c) logit += vr[c] * fcw[c];
        float x = 1.1f * logit;
        float sp = fmaxf(x, 0.f) + log1pf(expf(-fabsf(x)));   // stable softplus
        float t  = sp / 1.1f;
        float inv = 1.0f / t;
        #pragma unroll
        for (int c = 0; c < 10; ++c) out[(size_t)b * 10 + c] = vr[c] * inv;
    }
}

extern "C" void kernel_launch(void* const* d_in, const int* in_sizes, int n_in,
                              void* d_out, int out_size, void* d_ws, size_t ws_size,
                              hipStream_t stream) {
    const float* num_x   = (const float*)d_in[0];
    const float* cat_x   = (const float*)d_in[1];
    const float* ew      = (const float*)d_in[2];
    const float* vanilla = (const float*)d_in[3];
    const float* conv_w  = (const float*)d_in[4];
    const float* emb_w   = (const float*)d_in[5];
    const float* fc_w    = (const float*)d_in[6];
    const float* fc_b    = (const float*)d_in[7];
    const int*   ei      = (const int*)d_in[8];
    const int*   rowi    = ei;        // edge_index[0]
    const int*   coli    = ei + NE;   // edge_index[1]

    float* ws     = (float*)d_ws;
    ull*   dc     = (ull*)ws;                 // 100000 x 8B — dead after k_dis
    float* dis    = ws + 200000;              // 100000
    float* catf   = ws + 300000;              // 512
    float* pooled = ws + 300512;              // 128
    float* sbase  = ws + 300640;              // 64 (pad)
    int*   cnt    = (int*)(ws + 300704);      // 100000
    int*   offs   = (int*)(ws + 400704);      // 100001 (pad to 100064)
    int*   rank   = (int*)(ws + 500768);      // 1600000 ints (6.4 MB)
    uint*  sorted = (uint*)(ws + 2100768);    // 1600000 uints (6.4 MB)
    uint*  xwb    = (uint*)(ws + 3700768);    // 6400000 uints (25.6 MB, 16B-aligned)
    int*   bsum   = (int*)(ws + 10100768);    // 391 ints (past xwb — dc is LIVE
    int*   boff   = (int*)(ws + 10101280);    // 391 ints  during fused k_dis)
    float* out    = (float*)d_out;

    k_init  <<<391,  256, 0, stream>>>(dc, pooled, offs, cat_x, emb_w, catf);
    k_degcnt<<<6250, 256, 0, stream>>>(coli, ew, dc, rank);
    k_dis   <<<391,  256, 0, stream>>>(dc, dis, cnt, bsum);
    k_scan2 <<<1,    512, 0, stream>>>(bsum, boff);
    k_scan3 <<<391,  256, 0, stream>>>(cnt, boff, offs);
    k_gemm  <<<782,  256, 0, stream>>>(num_x, catf, conv_w, xwb);
    k_fill  <<<6250, 256, 0, stream>>>(rowi, coli, ew, dis, offs, rank, sorted);
    k_gather<<<2048, 256, 0, stream>>>((const uint4*)xwb, dis, sorted, offs, pooled);
    k_scal  <<<1,    64,  0, stream>>>(pooled, fc_w, fc_b, sbase);
    k_out   <<<16,   256, 0, stream>>>(vanilla, fc_w, sbase, out);
}